// Round 4
// baseline (498.361 us; speedup 1.0000x reference)
//
#include <hip/hip_runtime.h>
#include <math.h>

#define N_NODES 50000
#define N_EDGES 800000
#define C 64
#define H 4
#define D 16
#define HC 256
#define BN_EPS 1e-5f
#define NCHUNK 49            // ceil(N_NODES / 1024)
#define LOG2E 1.44269504f

// 16-lane (DPP row) rotate-add; after ror8,ror4,ror2,ror1 every lane holds the row sum.
template <int CTRL>
__device__ __forceinline__ float ror_add(float x) {
    int y = __builtin_amdgcn_update_dpp(0, __float_as_int(x), CTRL, 0xF, 0xF, true);
    return x + __int_as_float(y);
}
__device__ __forceinline__ float row_reduce(float u) {
    u = ror_add<0x128>(u);  // ror 8
    u = ror_add<0x124>(u);  // ror 4
    u = ror_add<0x122>(u);  // ror 2
    u = ror_add<0x121>(u);  // ror 1
    return u;
}

__device__ __forceinline__ float fast_exp2(float x) {
    float r;
    asm("v_exp_f32 %0, %1" : "=v"(r) : "v"(x));
    return r;
}

// leaky_relu(z, 0.2) == 0.6*z + 0.4*|z|
__device__ __forceinline__ float lrelu(float z) {
    return fmaf(0.4f, fabsf(z), 0.6f * z);
}

// ---------------- projection, DS-free: W columns in VGPRs, x rows via uniform loads ----
// thread owns 2 columns of the concatenated [W_l | W_r] (512 cols): w*128+lane, +64.
__global__ void __launch_bounds__(256) proj2_kernel(const float* __restrict__ x,
                                                    const float* __restrict__ Wl,
                                                    const float* __restrict__ Wr,
                                                    float* __restrict__ xl,
                                                    float* __restrict__ xr) {
    int tid = threadIdx.x;
    int lane = tid & 63;
    int w = tid >> 6;
    int gc0 = w * 128 + lane;
    int gc1 = gc0 + 64;

    float wa[C], wb[C];
    {
        const float* W0 = (gc0 < HC) ? (Wl + gc0) : (Wr + (gc0 - HC));
        const float* W1 = (gc1 < HC) ? (Wl + gc1) : (Wr + (gc1 - HC));
#pragma unroll
        for (int k = 0; k < C; ++k) {
            wa[k] = W0[(size_t)k * HC];
            wb[k] = W1[(size_t)k * HC];
        }
    }

    for (int r = blockIdx.x; r < N_NODES; r += gridDim.x) {
        const float* xrow = x + ((size_t)__builtin_amdgcn_readfirstlane(r) << 6);
        float acc0 = 0.f, acc1 = 0.f;
#pragma unroll
        for (int k = 0; k < C; ++k) {
            float xv = xrow[k];
            acc0 = fmaf(xv, wa[k], acc0);
            acc1 = fmaf(xv, wb[k], acc1);
        }
        float* o0 = (gc0 < HC) ? (xl + (size_t)r * HC + gc0) : (xr + (size_t)r * HC + (gc0 - HC));
        float* o1 = (gc1 < HC) ? (xl + (size_t)r * HC + gc1) : (xr + (size_t)r * HC + (gc1 - HC));
        *o0 = acc0;
        *o1 = acc1;
    }
}

// ---------------- per-dst edge counts ----------------
__global__ void __launch_bounds__(256) cnt_kernel(const int* __restrict__ dst,
                                                  int* __restrict__ cnt) {
    int e = blockIdx.x * 256 + threadIdx.x;
    if (e < N_EDGES) atomicAdd(&cnt[dst[e]], 1);
}

// ---------------- parallel scan: A) per-chunk sums ----------------
__global__ void __launch_bounds__(256) scanA_kernel(const int* __restrict__ cnt,
                                                    int* __restrict__ part) {
    __shared__ int red[256];
    int b = blockIdx.x, tid = threadIdx.x;
    int base = b * 1024 + tid;
    int s = 0;
#pragma unroll
    for (int q = 0; q < 4; ++q) {
        int g = base + q * 256;
        s += (g < N_NODES) ? cnt[g] : 0;
    }
    red[tid] = s;
    __syncthreads();
    if (tid < 128) red[tid] += red[tid + 128];
    __syncthreads();
    if (tid < 64) {
        int v = red[tid] + red[tid + 64];
#pragma unroll
        for (int o = 32; o > 0; o >>= 1) v += __shfl_xor(v, o, 64);
        if (tid == 0) part[b] = v;
    }
}

// ---------------- B) scan the 49 partials (1 wave), in-place exclusive ----------------
__global__ void scanB_kernel(int* __restrict__ part) {
    int lane = threadIdx.x;
    int v = (lane < NCHUNK) ? part[lane] : 0;
    int xv = v;
    for (int o = 1; o < 64; o <<= 1) {
        int t = __shfl_up(xv, o, 64);
        if (lane >= o) xv += t;
    }
    if (lane < NCHUNK) part[lane] = xv - v;
}

// ---------------- C) per-chunk local scan + base ----------------
__global__ void scanC_kernel(const int* __restrict__ cnt, const int* __restrict__ part,
                             int* __restrict__ off) {
    __shared__ int wsum[16];
    int b = blockIdx.x, tid = threadIdx.x;
    int lane = tid & 63, w = tid >> 6;
    int i = b * 1024 + tid;
    int v = (i < N_NODES) ? cnt[i] : 0;
    int xv = v;
    for (int o = 1; o < 64; o <<= 1) {
        int t = __shfl_up(xv, o, 64);
        if (lane >= o) xv += t;
    }
    if (lane == 63) wsum[w] = xv;
    __syncthreads();
    if (tid < 16) {
        int y = wsum[tid];
        for (int o = 1; o < 16; o <<= 1) {
            int t = __shfl_up(y, o, 64);
            if (tid >= o) y += t;
        }
        wsum[tid] = y;
    }
    __syncthreads();
    int prefix = part[b] + ((w > 0) ? wsum[w - 1] : 0);
    if (i < N_NODES) off[i + 1] = prefix + xv;
    if (b == 0 && tid == 0) off[0] = 0;
}

// ---------------- CSR fill: (edge id, src id) packed per slot ----------------
__global__ void __launch_bounds__(256) csr_fill_kernel(const int* __restrict__ src,
                                                       const int* __restrict__ dst,
                                                       const int* __restrict__ csr_off,
                                                       int* __restrict__ fill,
                                                       int2* __restrict__ csr_es) {
    int e = blockIdx.x * 256 + threadIdx.x;
    if (e >= N_EDGES) return;
    int d = dst[e];
    int pos = csr_off[d] + atomicAdd(&fill[d], 1);
    csr_es[pos] = make_int2(e, src[e]);
}

// ---------------- fused GATv2: one wave per node, 2-slot pipelined edge loop ----------------
__global__ void __launch_bounds__(256) fused_kernel(const int* __restrict__ csr_off,
                                                    const int2* __restrict__ csr_es,
                                                    const float* __restrict__ ea,
                                                    const float* __restrict__ xl,
                                                    const float* __restrict__ xr,
                                                    const float* __restrict__ We,
                                                    const float* __restrict__ att,
                                                    const float* __restrict__ bias,
                                                    float* __restrict__ out) {
    int gtid = blockIdx.x * blockDim.x + threadIdx.x;
    int gw = gtid >> 6;
    int nw = (gridDim.x * blockDim.x) >> 6;
    int lane = threadIdx.x & 63;
    int c0 = lane & 15;
    int colbase = (lane >> 4) * C + c0 * 4;

    // per-lane weight columns: We[k][colbase + 0..3], k = 0..15 (64 VGPRs)
    float w0[D], w1[D], w2[D], w3[D];
#pragma unroll
    for (int k = 0; k < D; ++k) {
        float4 wv = *(const float4*)(We + (size_t)k * HC + colbase);
        w0[k] = wv.x; w1[k] = wv.y; w2[k] = wv.z; w3[k] = wv.w;
    }
    float4 av = *(const float4*)(att + colbase);
    av.x *= LOG2E; av.y *= LOG2E; av.z *= LOG2E; av.w *= LOG2E;   // logits in log2 domain

    for (int i = gw; i < N_NODES; i += nw) {
        int off = csr_off[i];
        int deg = csr_off[i + 1] - off;
        float4 xrt = *(const float4*)(xr + ((size_t)i << 8) + colbase);

        float m = -3.0e38f, den = 0.f;
        float a0 = 0.f, a1 = 0.f, a2 = 0.f, a3 = 0.f;
        float s0 = 0.f, s1 = 0.f, s2 = 0.f, s3 = 0.f;

        float4 eavA[4], eavB[4], xsA, xsB;

        auto issue = [&](float4 (&ev)[4], float4& xs, int2 es) {
            int e    = __builtin_amdgcn_readfirstlane(es.x);
            int sidx = __builtin_amdgcn_readfirstlane(es.y);
            const float4* er = (const float4*)(ea + ((size_t)e << 4));
            ev[0] = er[0]; ev[1] = er[1]; ev[2] = er[2]; ev[3] = er[3];
            xs = *(const float4*)(xl + ((size_t)sidx << 8) + colbase);
        };

        auto compute_u = [&](const float4 (&ev)[4], const float4 xs) -> float {
            float e0 = 0.f, e1 = 0.f, e2 = 0.f, e3 = 0.f;
#pragma unroll
            for (int q = 0; q < 4; ++q) {
                float4 eq = ev[q];
                e0 = fmaf(eq.x, w0[4*q+0], e0); e1 = fmaf(eq.x, w1[4*q+0], e1);
                e2 = fmaf(eq.x, w2[4*q+0], e2); e3 = fmaf(eq.x, w3[4*q+0], e3);
                e0 = fmaf(eq.y, w0[4*q+1], e0); e1 = fmaf(eq.y, w1[4*q+1], e1);
                e2 = fmaf(eq.y, w2[4*q+1], e2); e3 = fmaf(eq.y, w3[4*q+1], e3);
                e0 = fmaf(eq.z, w0[4*q+2], e0); e1 = fmaf(eq.z, w1[4*q+2], e1);
                e2 = fmaf(eq.z, w2[4*q+2], e2); e3 = fmaf(eq.z, w3[4*q+2], e3);
                e0 = fmaf(eq.w, w0[4*q+3], e0); e1 = fmaf(eq.w, w1[4*q+3], e1);
                e2 = fmaf(eq.w, w2[4*q+3], e2); e3 = fmaf(eq.w, w3[4*q+3], e3);
            }
            s0 += e0; s1 += e1; s2 += e2; s3 += e3;
            float z0 = e0 + xs.x + xrt.x;
            float z1 = e1 + xs.y + xrt.y;
            float z2 = e2 + xs.z + xrt.z;
            float z3 = e3 + xs.w + xrt.w;
            float u = lrelu(z0) * av.x;
            u = fmaf(lrelu(z1), av.y, u);
            u = fmaf(lrelu(z2), av.z, u);
            u = fmaf(lrelu(z3), av.w, u);
            return row_reduce(u);
        };

        auto upd2 = [&](float u0, float u1, float4 xA, float4 xB) {
            float mn = fmaxf(m, fmaxf(u0, u1));
            float so = fast_exp2(m - mn);
            float wA = fast_exp2(u0 - mn);
            float wB = fast_exp2(u1 - mn);
            den = fmaf(den, so, wA + wB);
            a0 = fmaf(a0, so, fmaf(wA, xA.x, wB * xB.x));
            a1 = fmaf(a1, so, fmaf(wA, xA.y, wB * xB.y));
            a2 = fmaf(a2, so, fmaf(wA, xA.z, wB * xB.z));
            a3 = fmaf(a3, so, fmaf(wA, xA.w, wB * xB.w));
            m = mn;
        };
        auto upd1 = [&](float u, float4 xs) {
            float mn = fmaxf(m, u);
            float so = fast_exp2(m - mn);
            float wt = fast_exp2(u - mn);
            den = fmaf(den, so, wt);
            a0 = fmaf(a0, so, wt * xs.x);
            a1 = fmaf(a1, so, wt * xs.y);
            a2 = fmaf(a2, so, wt * xs.z);
            a3 = fmaf(a3, so, wt * xs.w);
            m = mn;
        };

        if (deg > 0) issue(eavA, xsA, csr_es[off]);
        if (deg > 1) issue(eavB, xsB, csr_es[off + 1]);

        int j = 0;
        for (; j + 3 < deg; j += 2) {
            int2 esA2 = csr_es[off + j + 2];
            int2 esB2 = csr_es[off + j + 3];
            float u0 = compute_u(eavA, xsA);
            float4 xA = xsA;
            issue(eavA, xsA, esA2);          // prefetch pair k+1 slot A
            float u1 = compute_u(eavB, xsB);
            float4 xB = xsB;
            issue(eavB, xsB, esB2);          // prefetch pair k+1 slot B
            upd2(u0, u1, xA, xB);
        }
        int r = deg - j;
        if (r >= 2) {
            float u0 = compute_u(eavA, xsA);
            float u1 = compute_u(eavB, xsB);
            if (r == 3) {
                float4 xA = xsA, xB = xsB;
                int2 esC = csr_es[off + j + 2];
                issue(eavA, xsA, esC);
                upd2(u0, u1, xA, xB);
                float u2 = compute_u(eavA, xsA);
                upd1(u2, xsA);
            } else {
                upd2(u0, u1, xsA, xsB);
            }
        } else if (r == 1) {
            float u0 = compute_u(eavA, xsA);
            upd1(u0, xsA);
        }

        // ---- self loop: ee_self = mean(ee_j) by linearity ----
        float4 xli = *(const float4*)(xl + ((size_t)i << 8) + colbase);
        float dninv = 1.f / fmaxf((float)deg, 1.f);
        {
            float z0 = fmaf(s0, dninv, xli.x + xrt.x);
            float z1 = fmaf(s1, dninv, xli.y + xrt.y);
            float z2 = fmaf(s2, dninv, xli.z + xrt.z);
            float z3 = fmaf(s3, dninv, xli.w + xrt.w);
            float u = lrelu(z0) * av.x;
            u = fmaf(lrelu(z1), av.y, u);
            u = fmaf(lrelu(z2), av.z, u);
            u = fmaf(lrelu(z3), av.w, u);
            u = row_reduce(u);
            float mn = fmaxf(m, u);
            float so = fast_exp2(m - mn);
            float wt = fast_exp2(u - mn);
            den = fmaf(den, so, wt);
            a0 = fmaf(a0, so, wt * xli.x);
            a1 = fmaf(a1, so, wt * xli.y);
            a2 = fmaf(a2, so, wt * xli.z);
            a3 = fmaf(a3, so, wt * xli.w);
        }

        // ---- normalize, head mean, bias, store ----
        float inv = 1.f / den;
        float r0 = a0 * inv, r1 = a1 * inv, r2 = a2 * inv, r3 = a3 * inv;
        r0 += __shfl_xor(r0, 16); r0 += __shfl_xor(r0, 32);
        r1 += __shfl_xor(r1, 16); r1 += __shfl_xor(r1, 32);
        r2 += __shfl_xor(r2, 16); r2 += __shfl_xor(r2, 32);
        r3 += __shfl_xor(r3, 16); r3 += __shfl_xor(r3, 32);
        if (lane < 16) {
            float4 bv = *(const float4*)(bias + c0 * 4);
            float4 o;
            o.x = fmaf(r0, 0.25f, bv.x);
            o.y = fmaf(r1, 0.25f, bv.y);
            o.z = fmaf(r2, 0.25f, bv.z);
            o.w = fmaf(r3, 0.25f, bv.w);
            *(float4*)(out + (size_t)i * C + c0 * 4) = o;
        }
    }
}

// ---------------- BN statistics (sum, sumsq per channel) ----------------
__global__ void __launch_bounds__(256) bn_stats_kernel(const float* __restrict__ out,
                                                       float* __restrict__ bn) {
    int tid = threadIdx.x;
    int c = tid & 63;
    int r0 = blockIdx.x * 256 + (tid >> 6);
    int rend = (blockIdx.x * 256 + 256 < N_NODES) ? blockIdx.x * 256 + 256 : N_NODES;
    float s = 0.f, s2 = 0.f;
    for (int r = r0; r < rend; r += 4) {
        float v = out[(size_t)r * C + c];
        s += v; s2 += v * v;
    }
    __shared__ float red[256], red2[256];
    red[tid] = s; red2[tid] = s2;
    __syncthreads();
    if (tid < 128) { red[tid] += red[tid + 128]; red2[tid] += red2[tid + 128]; }
    __syncthreads();
    if (tid < 64) {
        atomicAdd(&bn[c], red[tid] + red[tid + 64]);
        atomicAdd(&bn[64 + c], red2[tid] + red2[tid + 64]);
    }
}

// ---------------- BN normalize + residual + ReLU (in place on out) ----------------
__global__ void __launch_bounds__(256) final_kernel(const float* __restrict__ x,
                                                    const float* __restrict__ bn,
                                                    const float* __restrict__ gamma,
                                                    const float* __restrict__ beta,
                                                    float* __restrict__ out) {
    int idx = blockIdx.x * 256 + threadIdx.x;
    if (idx >= N_NODES * C) return;
    int c = idx & 63;
    float mu = bn[c] * (1.f / N_NODES);
    float var = bn[64 + c] * (1.f / N_NODES) - mu * mu;
    float o = out[idx];
    float y = gamma[c] * (o - mu) * rsqrtf(var + BN_EPS) + beta[c] + x[idx];
    out[idx] = fmaxf(y, 0.f);
}

extern "C" void kernel_launch(void* const* d_in, const int* in_sizes, int n_in,
                              void* d_out, int out_size, void* d_ws, size_t ws_size,
                              hipStream_t stream) {
    const float* x     = (const float*)d_in[0];
    const int*   ei    = (const int*)d_in[1];
    const float* ea    = (const float*)d_in[2];
    const float* W_l   = (const float*)d_in[3];
    const float* W_r   = (const float*)d_in[4];
    const float* W_e   = (const float*)d_in[5];
    const float* att   = (const float*)d_in[6];
    const float* bias  = (const float*)d_in[7];
    const float* gamma = (const float*)d_in[8];
    const float* beta  = (const float*)d_in[9];
    float* out = (float*)d_out;

    const int* src = ei;
    const int* dst = ei + N_EDGES;

    char* p = (char*)d_ws;
    float* bn      = (float*)p; p += 512;
    int*   cnt     = (int*)p;   p += (size_t)N_NODES * 4;
    int*   fill    = (int*)p;   p += (size_t)N_NODES * 4;
    int*   csr_off = (int*)p;   p += (size_t)(N_NODES + 4) * 4;
    int*   part    = (int*)p;   p += 256;
    int2*  csr_es  = (int2*)p;  p += (size_t)N_EDGES * 8;
    float* xl      = (float*)p; p += (size_t)N_NODES * HC * 4;
    float* xr      = (float*)p; p += (size_t)N_NODES * HC * 4;

    // zero bn + cnt + fill (contiguous)
    hipMemsetAsync(bn, 0, 512 + 2 * (size_t)N_NODES * 4, stream);

    proj2_kernel<<<1024, 256, 0, stream>>>(x, W_l, W_r, xl, xr);
    cnt_kernel<<<(N_EDGES + 255) / 256, 256, 0, stream>>>(dst, cnt);
    scanA_kernel<<<NCHUNK, 256, 0, stream>>>(cnt, part);
    scanB_kernel<<<1, 64, 0, stream>>>(part);
    scanC_kernel<<<NCHUNK, 1024, 0, stream>>>(cnt, part, csr_off);
    csr_fill_kernel<<<(N_EDGES + 255) / 256, 256, 0, stream>>>(src, dst, csr_off, fill,
                                                               csr_es);
    fused_kernel<<<2048, 256, 0, stream>>>(csr_off, csr_es, ea, xl, xr, W_e, att, bias,
                                           out);
    bn_stats_kernel<<<(N_NODES + 255) / 256, 256, 0, stream>>>(out, bn);
    final_kernel<<<(N_NODES * C) / 256, 256, 0, stream>>>(x, bn, gamma, beta, out);
}